// Round 10
// baseline (58.134 us; speedup 1.0000x reference)
//
#include <hip/hip_runtime.h>
#include <hip/hip_bf16.h>

// Problem constants
constexpr int   D      = 512;
constexpr float ALPHA  = 1.0f;
constexpr float EPS    = 1e-9f;
constexpr float INV_CNT = 1.0f / (32.0f * 128.0f * 128.0f);  // 1/524288

// ws layout (bytes)
constexpr size_t PART_OFF = 0;       // 256*4
constexpr size_t CNT_OFF  = 1024;    // int counter (memset to 0 each call)

typedef short bf16x8 __attribute__((ext_vector_type(8)));
typedef float f32x4  __attribute__((ext_vector_type(4)));

// f32 -> bf16 (RNE); compiler fuses pairs into v_cvt_pk_bf16_f32 (m240)
__device__ __forceinline__ short fb(float x) {
    __hip_bfloat16 h = __float2bfloat16(x);
    return __builtin_bit_cast(short, h);
}
__device__ __forceinline__ bf16x8 cvt8(float4 lo, float4 hi) {
    bf16x8 r;
    r[0] = fb(lo.x); r[1] = fb(lo.y); r[2] = fb(lo.z); r[3] = fb(lo.w);
    r[4] = fb(hi.x); r[5] = fb(hi.y); r[6] = fb(hi.z); r[7] = fb(hi.w);
    return r;
}

// ---------------------------------------------------------------------------
// Single kernel. grid = 256 blocks x 512 threads (8 waves, R8's proven shape).
// Phase N: block computes norms of its batch's 256 raw rows -> inv[] in LDS.
// Phase G: P_raw = [t16;c16].[t;c]^T on raw-bf16 (normalization deferred):
//   A: direct f32 loads + convert, 2-set reg pipeline (distance 2).
//   B: f32 loads -> convert -> ds_write (wave-private double buffer, no
//      barriers; write-side XOR swizzle, 1 ds_read_b128 per fragment).
// Phase L: loss with inv_i*inv_j scaling folded in; bitonic sort + prefix +
//   binary-search closed form (verified rounds 3-9).
// Phase R: last block (atomic counter) reduces 256 partials -> out[0].
constexpr int PSTR = 260;   // padded f32 row stride for P

__global__ __launch_bounds__(512, 2) void k_all(const float* __restrict__ lat,
                                                float* __restrict__ part,
                                                int* __restrict__ counter,
                                                float* __restrict__ out) {
    // [0,32768): B arena (2 bufs x 8 waves x 2KB). P overlays [0,33280).
    // inv[256] @33280 (disjoint from arena AND P). red @34304.
    __shared__ __align__(16) char smem[34368];
    __shared__ int lastflag;

    const int p     = blockIdx.x;
    const int slot  = p >> 3;
    const int b     = (p & 7) * 4 + (slot & 3);   // XCD-bijective: 4 batches/XCD
    const int chunk = slot >> 2;
    const int w     = threadIdx.x >> 6;
    const int lane  = threadIdx.x & 63;
    const int fr    = lane & 15;
    const int kg    = lane >> 4;

    const float* latb = lat + (size_t)b * 256 * D;
    float* invp = (float*)&smem[33280];
    float* red  = (float*)&smem[34304];

    // ---------------- Phase N: 256 row norms (wave w: rows w*32..+31) -------
    {
        const float4* l4 = (const float4*)latb;
        #pragma unroll 2
        for (int rr = 0; rr < 32; rr += 2) {
            const int r0 = w * 32 + rr;
            float4 x0 = l4[r0 * 128 + 2 * lane];
            float4 x1 = l4[r0 * 128 + 2 * lane + 1];
            float4 y0 = l4[(r0 + 1) * 128 + 2 * lane];
            float4 y1 = l4[(r0 + 1) * 128 + 2 * lane + 1];
            float s0 = x0.x*x0.x + x0.y*x0.y + x0.z*x0.z + x0.w*x0.w
                     + x1.x*x1.x + x1.y*x1.y + x1.z*x1.z + x1.w*x1.w;
            float s1 = y0.x*y0.x + y0.y*y0.y + y0.z*y0.z + y0.w*y0.w
                     + y1.x*y1.x + y1.y*y1.y + y1.z*y1.z + y1.w*y1.w;
            #pragma unroll
            for (int o = 32; o > 0; o >>= 1) {
                s0 += __shfl_xor(s0, o, 64);
                s1 += __shfl_xor(s1, o, 64);
            }
            if (lane == 0) {
                invp[r0]     = rsqrtf(s0);
                invp[r0 + 1] = rsqrtf(s1);
            }
        }
    }
    // inv consumed only after the post-MFMA __syncthreads (visibility covered).

    // ---------------- Phase G: MFMA on raw-bf16 -----------------------------
    const int cg = w * 32;                        // this wave's 32 B-rows
    const float* gA0 = latb + (size_t)(chunk * 16 + fr) * D + 8 * kg;
    const float* gA1 = gA0 + (size_t)128 * D;
    // B per-lane source: row cg+(lane>>1), k-half lane&1 (64 B per slice)
    const float* gB = latb + (size_t)(cg + (lane >> 1)) * D + (lane & 1) * 16;

    char* wb0 = &smem[0     + w * 2048];          // wave-private buf 0
    char* wb1 = &smem[16384 + w * 2048];          // wave-private buf 1

    const int brow = lane >> 1, bh = lane & 1;
    // write: [32 rows][64B], 16B slot c of half bh at pos (2bh+c)^(row&3)
    const int wo0 = brow * 64 + (((2 * bh + 0) ^ (brow & 3)) * 16);
    const int wo1 = brow * 64 + (((2 * bh + 1) ^ (brow & 3)) * 16);
    // read: b0 row fr slot kg -> pos kg^(fr&3); b1 row 16+fr (same &3)
    const int ro0 = fr * 64 + ((kg ^ (fr & 3)) * 16);
    const int ro1 = ro0 + 1024;

    float4 As[2][4], Bs[2][4];                    // static idx after unroll
    f32x4 acc00 = {0.f,0.f,0.f,0.f}, acc01 = {0.f,0.f,0.f,0.f};
    f32x4 acc10 = {0.f,0.f,0.f,0.f}, acc11 = {0.f,0.f,0.f,0.f};

    auto LOADA = [&](int s, int st) {
        As[st][0] = *(const float4*)(gA0 + s * 32);
        As[st][1] = *(const float4*)(gA0 + s * 32 + 4);
        As[st][2] = *(const float4*)(gA1 + s * 32);
        As[st][3] = *(const float4*)(gA1 + s * 32 + 4);
    };
    auto LOADB = [&](int s, int st) {
        Bs[st][0] = *(const float4*)(gB + s * 32);
        Bs[st][1] = *(const float4*)(gB + s * 32 + 4);
        Bs[st][2] = *(const float4*)(gB + s * 32 + 8);
        Bs[st][3] = *(const float4*)(gB + s * 32 + 12);
    };
    auto WRITEB = [&](int st, char* buf) {
        *(bf16x8*)(buf + wo0) = cvt8(Bs[st][0], Bs[st][1]);
        *(bf16x8*)(buf + wo1) = cvt8(Bs[st][2], Bs[st][3]);
    };

    LOADA(0, 0); LOADB(0, 0);
    LOADA(1, 1); LOADB(1, 1);
    WRITEB(0, wb0);

    #pragma unroll
    for (int s = 0; s < 16; s++) {
        const int sp = s & 1;
        char* rb = sp ? wb1 : wb0;                // buf holding slice s
        char* nb = sp ? wb0 : wb1;                // buf for slice s+1
        bf16x8 af0 = cvt8(As[sp][0], As[sp][1]);  // consume A(s) before reload
        bf16x8 af1 = cvt8(As[sp][2], As[sp][3]);
        if (s < 14) { LOADA(s + 2, sp); LOADB(s + 2, sp); }
        if (s < 15) WRITEB(sp ^ 1, nb);           // slice s+1 -> other buf
        bf16x8 b0 = *(const bf16x8*)(rb + ro0);
        bf16x8 b1 = *(const bf16x8*)(rb + ro1);
        acc00 = __builtin_amdgcn_mfma_f32_16x16x32_bf16(af0, b0, acc00, 0, 0, 0);
        acc01 = __builtin_amdgcn_mfma_f32_16x16x32_bf16(af0, b1, acc01, 0, 0, 0);
        acc10 = __builtin_amdgcn_mfma_f32_16x16x32_bf16(af1, b0, acc10, 0, 0, 0);
        acc11 = __builtin_amdgcn_mfma_f32_16x16x32_bf16(af1, b1, acc11, 0, 0, 0);
    }

    __syncthreads();   // B arena dead; P overlays it

    float* P = (float*)smem;                      // 32 x PSTR f32 = 33280 B

    // C/D layout (m89-verified): lane l, reg q -> row (l>>4)*4+q, col l&15
    {
        const int rw = kg * 4;
        const int cw = cg + fr;
        #pragma unroll
        for (int q = 0; q < 4; q++) P[(rw + q) * PSTR + cw]            = acc00[q];
        #pragma unroll
        for (int q = 0; q < 4; q++) P[(rw + q) * PSTR + cw + 16]      = acc01[q];
        #pragma unroll
        for (int q = 0; q < 4; q++) P[(16 + rw + q) * PSTR + cw]      = acc10[q];
        #pragma unroll
        for (int q = 0; q < 4; q++) P[(16 + rw + q) * PSTR + cw + 16] = acc11[q];
    }
    __syncthreads();

    // ---------------- Phase L: loss, 4 rows/wave (verified structure) -------
    float wacc = 0.f;
    #pragma unroll
    for (int rr = 0; rr < 4; rr++) {
        const int r      = w * 4 + rr;
        const int pd_off = (r < 16) ? 0 : 128;
        const int pn_off = 128 - pd_off;
        float* prow = &P[r * PSTR];

        // deferred normalization: scale by inv_row * inv_col
        const float invA = invp[(r < 16) ? (chunk * 16 + r)
                                         : (128 + chunk * 16 + (r - 16))];
        const float g0 = prow[pd_off + lane]      * invA * invp[pd_off + lane];
        const float g1 = prow[pd_off + lane + 64] * invA * invp[pd_off + lane + 64];
        float v0 = prow[pn_off + lane]      * invA * invp[pn_off + lane];
        float v1 = prow[pn_off + lane + 64] * invA * invp[pn_off + lane + 64];

        // bitonic sort ascending (2 elems/lane)
        #pragma unroll
        for (int kk = 2; kk <= 128; kk <<= 1) {
            if (kk == 128) {
                const float lo = fminf(v0, v1);
                const float hi = fmaxf(v0, v1);
                v0 = lo; v1 = hi;
            }
            #pragma unroll
            for (int j = (kk == 128 ? 32 : (kk >> 1)); j >= 1; j >>= 1) {
                const float p0 = __shfl_xor(v0, j, 64);
                const float p1 = __shfl_xor(v1, j, 64);
                const bool up0 = (lane & kk) == 0;
                const bool up1 = ((lane + 64) & kk) == 0;
                const bool lower = (lane & j) == 0;
                v0 = (up0 == lower) ? fminf(v0, p0) : fmaxf(v0, p0);
                v1 = (up1 == lower) ? fminf(v1, p1) : fmaxf(v1, p1);
            }
        }

        // inclusive prefix scans of the two halves
        float inc0 = v0, inc1 = v1;
        #pragma unroll
        for (int o = 1; o < 64; o <<= 1) {
            const float t0 = __shfl_up(inc0, o, 64);
            const float t1 = __shfl_up(inc1, o, 64);
            if (lane >= o) { inc0 += t0; inc1 += t1; }
        }
        const float tot0  = __shfl(inc0, 63, 64);
        const float total = tot0 + __shfl(inc1, 63, 64);

        // write sorted s[0:128] and exclusive prefix pre[0:129]
        prow[lane]            = v0;
        prow[64 + lane]       = v1;
        prow[130 + 1 + lane]  = inc0;
        prow[130 + 65 + lane] = tot0 + inc1;
        if (lane == 0) prow[130] = 0.f;

        // per-j: rank via guarded binary search, closed-form num/den
        #pragma unroll
        for (int h = 0; h < 2; h++) {
            const float g   = h ? g1 : g0;
            const float tau = g - 0.5f * ALPHA;   // v>0 <=> h_k > tau
            const float a   = ALPHA - 2.f * g;
            int pos = 0;
            #pragma unroll
            for (int st = 128; st > 0; st >>= 1) {
                const int nidx = pos + st;
                const float sv = prow[nidx - 1];
                pos = ((nidx <= 128) && (sv <= tau)) ? nidx : pos;
            }
            const float cnt = (float)(128 - pos);
            const float pre = prow[130 + pos];
            const float num = cnt * a + 2.f * (total - pre);
            wacc += num / (cnt + EPS);
        }
    }

    #pragma unroll
    for (int o = 32; o > 0; o >>= 1) wacc += __shfl_xor(wacc, o, 64);
    if (lane == 0) red[w] = wacc;
    __syncthreads();
    if (threadIdx.x == 0) {
        float s = 0.f;
        #pragma unroll
        for (int i = 0; i < 8; i++) s += red[i];
        part[p] = s;
        __threadfence();                          // release part[p]
        lastflag = atomicAdd(counter, 1);         // device-scope
    }
    __syncthreads();

    // ---------------- Phase R: last block reduces 256 partials --------------
    if (lastflag == 255) {
        __threadfence();                          // acquire
        float s = (threadIdx.x < 256) ? part[threadIdx.x] : 0.f;
        #pragma unroll
        for (int o = 32; o > 0; o >>= 1) s += __shfl_xor(s, o, 64);
        if (lane == 0) red[w] = s;
        __syncthreads();
        if (threadIdx.x == 0) {
            float t = 0.f;
            #pragma unroll
            for (int i = 0; i < 4; i++) t += red[i];
            out[0] = t * INV_CNT;
        }
    }
}

// ---------------------------------------------------------------------------
extern "C" void kernel_launch(void* const* d_in, const int* in_sizes, int n_in,
                              void* d_out, int out_size, void* d_ws, size_t ws_size,
                              hipStream_t stream) {
    const float* latent = (const float*)d_in[0];
    float* out  = (float*)d_out;
    char*  wsb  = (char*)d_ws;
    float* part = (float*)(wsb + PART_OFF);
    int*   cnt  = (int*)(wsb + CNT_OFF);

    hipMemsetAsync(cnt, 0, sizeof(int), stream);  // capture-legal memset node
    hipLaunchKernelGGL(k_all, dim3(256), dim3(512), 0, stream,
                       latent, part, cnt, out);
}